// Round 6
// baseline (1441.390 us; speedup 1.0000x reference)
//
#include <hip/hip_runtime.h>
#include <math.h>

#define BB 64
#define TT 1024
#define KK 128
#define START_TAG 126
#define CS 16              // timesteps per feat chunk
#define NCH (TT / CS)      // 64 chunks

typedef float v2f __attribute__((ext_vector_type(2)));
typedef float v4f __attribute__((ext_vector_type(4)));

// One wave per batch, zero barriers. Lane l owns rows l and l+64 of
// E[j][k] = exp(T[j][k] - maxT[j]), held wholly in VGPRs (256 regs).
// Step (exp-domain, deferred 1-step-stale normalization — validated exact in R4/R5):
//   d_j  = sum_k e_k E[j][k]          (128 pk_fma + 32 broadcast ds_read_b128)
//   sg   = d_{126} = sum_k e_k        (E row START is exactly 1.0; readlane 62)
//   u_j  = d_j * exp(feat[t][j]+maxT[j]) * rcp(sg_prev)
//   fwd  = feats[0,START] + ln2*( sum_{t<=L-2} log2 sg_t + log2 sg_L )
// u lives in one 512B LDS buffer; same-wave DS ordering makes the
// write(t) -> read(t+1) RAW safe with no barrier and no ping-pong.
// Feats are staged in 16-step chunks: loads for chunk c+2 issue right after
// the LDS stores of c+1, so vmcnt latency is hidden across a full chunk.
__global__ __launch_bounds__(64, 1) void crf_chain(
    const float* __restrict__ feats,   // [B,T,K]
    const int*   __restrict__ tags,    // [B,T]
    const int*   __restrict__ lens,    // [B]
    const float* __restrict__ trans,   // [K,K]
    float*       __restrict__ out_pb)  // [B]: forward - gold
{
  __shared__ __align__(16) float e_lds[KK];
  __shared__ float Fstage[2][CS][KK];             // raw feats, double-buffered

  const int lane = threadIdx.x;
  const int b    = blockIdx.x;
  const int Ln   = lens[b];
  const float* fb = feats + (size_t)b * TT * KK;

  // ---- E rows (l, l+64) into registers; per-row max; exp-normalize ----
  v2f E0[64], E1[64];
  float mT0 = -INFINITY, mT1 = -INFINITY;
  {
    const v4f* t0 = (const v4f*)(trans + lane * KK);
    const v4f* t1 = (const v4f*)(trans + (lane + 64) * KK);
    #pragma unroll
    for (int i = 0; i < 32; ++i) {
      const v4f a = t0[i], c = t1[i];
      E0[2*i]   = (v2f){a.x, a.y};  E0[2*i+1] = (v2f){a.z, a.w};
      E1[2*i]   = (v2f){c.x, c.y};  E1[2*i+1] = (v2f){c.z, c.w};
      mT0 = fmaxf(mT0, fmaxf(fmaxf(a.x, a.y), fmaxf(a.z, a.w)));
      mT1 = fmaxf(mT1, fmaxf(fmaxf(c.x, c.y), fmaxf(c.z, c.w)));
    }
    #pragma unroll
    for (int i = 0; i < 64; ++i) {
      E0[i][0] = __expf(E0[i][0] - mT0); E0[i][1] = __expf(E0[i][1] - mT0);
      E1[i][0] = __expf(E1[i][0] - mT1); E1[i][1] = __expf(E1[i][1] - mT1);
    }
  }

  // ---- init u(0) = onehot(START=126) ----
  e_lds[lane]      = 0.f;
  e_lds[lane + 64] = (lane == START_TAG - 64) ? 1.f : 0.f;

  // ---- feat staging pipeline ----
  float pf[32];
  auto loads = [&](int c) {
    #pragma unroll
    for (int i = 0; i < 32; ++i)
      pf[i] = fb[(size_t)(c * CS + (i & 15)) * KK + (i >> 4) * 64 + lane];
  };
  auto stores = [&](int c) {
    float* dst = &Fstage[c & 1][0][0];
    #pragma unroll
    for (int i = 0; i < 32; ++i)
      dst[(i & 15) * KK + (i >> 4) * 64 + lane] = pf[i];
  };
  loads(0); stores(0); loads(1);

  float sg_prev = 1.f, Macc = 0.f;
  const float M0 = fb[START_TAG];

  // ---- main recurrence: 1023 steps, no barriers ----
  for (int c = 0; c < NCH; ++c) {
    const float* Fc = &Fstage[c & 1][0][0];
    for (int tc = (c == 0) ? 1 : 0; tc < CS; ++tc) {
      const int t = c * CS + tc;
      const float rr = __builtin_amdgcn_rcpf(sg_prev);        // off-chain (stale)
      const float F0 = __expf(Fc[tc * KK + lane] + mT0);      // off-chain
      const float F1 = __expf(Fc[tc * KK + 64 + lane] + mT1);
      const v4f* e4 = (const v4f*)e_lds;
      v2f a00 = {0,0}, a01 = {0,0}, a10 = {0,0}, a11 = {0,0};
      #pragma unroll
      for (int i = 0; i < 32; ++i) {
        const v4f ev = e4[i];                                  // broadcast b128
        const v2f lo = __builtin_shufflevector(ev, ev, 0, 1);
        const v2f hi = __builtin_shufflevector(ev, ev, 2, 3);
        a00 = __builtin_elementwise_fma(lo, E0[2*i],     a00);
        a01 = __builtin_elementwise_fma(hi, E0[2*i + 1], a01);
        a10 = __builtin_elementwise_fma(lo, E1[2*i],     a10);
        a11 = __builtin_elementwise_fma(hi, E1[2*i + 1], a11);
      }
      const v2f sA = a00 + a01, sB = a10 + a11;
      const float d0 = sA[0] + sA[1];
      const float d1 = sB[0] + sB[1];
      const float sg = __int_as_float(
          __builtin_amdgcn_readlane(__float_as_int(d1), 62)); // row 126 = sum_k e_k
      e_lds[lane]      = d0 * (F0 * rr);
      e_lds[lane + 64] = d1 * (F1 * rr);
      Macc += ((t <= Ln - 2) || (t == Ln)) ? __log2f(sg) : 0.f; // off-chain
      sg_prev = sg;
    }
    if (c + 1 < NCH) stores(c + 1);
    if (c + 2 < NCH) loads(c + 2);
  }

  // ---- terminal: s_T = sum_k u(T-1) for batches with Ln == T ----
  float lu = e_lds[lane] + e_lds[lane + 64];
  #pragma unroll
  for (int m = 1; m < 64; m <<= 1) lu += __shfl_xor(lu, m, 64);
  if (Ln == TT) Macc += __log2f(lu);
  const float fwd = M0 + 0.69314718055994531f * Macc;

  // ---- gold score (same wave; 16 t's per lane) ----
  float g = 0.f;
  const int* tg = tags + b * TT;
  for (int t = lane; t < TT; t += 64) {
    if (t < Ln) {
      const int tag = tg[t];
      g += fb[(size_t)t * KK + tag];
      if (t < Ln - 1) g += trans[tg[t + 1] * KK + tag];
    }
  }
  #pragma unroll
  for (int m = 1; m < 64; m <<= 1) g += __shfl_xor(g, m, 64);
  if (lane == 0) out_pb[b] = fwd - g;
}

__global__ void crf_mean(const float* __restrict__ pb, float* __restrict__ out) {
  const int tid = threadIdx.x;  // 64 threads, one wave
  float v = pb[tid];
  #pragma unroll
  for (int m = 1; m < 64; m <<= 1) v += __shfl_xor(v, m, 64);
  if (tid == 0) out[0] = v * (1.0f / 64.0f);
}

extern "C" void kernel_launch(void* const* d_in, const int* in_sizes, int n_in,
                              void* d_out, int out_size, void* d_ws, size_t ws_size,
                              hipStream_t stream) {
  const float* feats = (const float*)d_in[0];
  const int*   tags  = (const int*)d_in[1];
  const int*   lens  = (const int*)d_in[2];
  const float* trans = (const float*)d_in[3];
  float* pb = (float*)d_ws;   // 64 floats of scratch
  crf_chain<<<BB, 64, 0, stream>>>(feats, tags, lens, trans, pb);
  crf_mean<<<1, 64, 0, stream>>>(pb, (float*)d_out);
}